// Round 1
// baseline (5872.669 us; speedup 1.0000x reference)
//
#include <hip/hip_runtime.h>

typedef unsigned int u32;
typedef unsigned long long u64;

#define N_PTS 65536
#define NB_ 25
#define NSAMP 2622            // ceil(65536/25)
#define FPS_BLOCKS 16
#define FPS_THREADS 1024
#define FPS_TOTAL (FPS_BLOCKS*FPS_THREADS)
#define PPT (N_PTS/FPS_TOTAL) // 4 points per thread
#define CAND_CAP 7900

static_assert(FPS_TOTAL*PPT == N_PTS, "fps partition");

__device__ __forceinline__ float dist2_exact(float px,float py,float pz,
                                             float qx,float qy,float qz){
  // numpy: ((dx*dx + dy*dy) + dz*dz), f32 round-to-nearest, NO fma contraction
  float dx=__fsub_rn(px,qx), dy=__fsub_rn(py,qy), dz=__fsub_rn(pz,qz);
  return __fadd_rn(__fadd_rn(__fmul_rn(dx,dx),__fmul_rn(dy,dy)),__fmul_rn(dz,dz));
}

// ---------------- K0: transpose points to SoA + init FPS comm ----------------
__global__ void k_setup(const float* __restrict__ pts, float* __restrict__ xs,
                        float* __restrict__ ys, float* __restrict__ zs,
                        u32* __restrict__ sample_inds, u64* __restrict__ partials){
  int i = blockIdx.x*blockDim.x + threadIdx.x;
  if (i < N_PTS){ xs[i]=pts[3*i]; ys[i]=pts[3*i+1]; zs[i]=pts[3*i+2]; }
  if (blockIdx.x==0){
    if (threadIdx.x < 4*FPS_BLOCKS) partials[threadIdx.x] = 0ULL; // SENT=0
    if (threadIdx.x==0) sample_inds[0] = 0u;
  }
}

// ---------------- K1: farthest point sampling (16 co-resident blocks) --------
__global__ void __launch_bounds__(FPS_THREADS) k_fps(
    const float* __restrict__ xs, const float* __restrict__ ys,
    const float* __restrict__ zs, u32* __restrict__ sample_inds,
    u64* __restrict__ partials)
{
  __shared__ float s_q[3];
  __shared__ u64 s_wmax[FPS_THREADS/64];
  const int tid  = threadIdx.x;
  const int b    = blockIdx.x;
  const int lane = tid & 63;
  const int wv   = tid >> 6;
  const int gt   = b*FPS_THREADS + tid;

  // L2 prewarm of SoA arrays (winner-coordinate loads hit local L2 later).
  float acc = 0.f;
  for (int j=tid; j<N_PTS; j+=FPS_THREADS) acc += xs[j]+ys[j]+zs[j];
  if (acc == -12345.678f && tid==0) sample_inds[0]=0u; // keep loads live; value correct anyway

  float px[PPT],py[PPT],pz[PPT],mind[PPT];
  #pragma unroll
  for (int k=0;k<PPT;k++){
    int i = k*FPS_TOTAL + gt;       // coalesced ownership
    px[k]=xs[i]; py[k]=ys[i]; pz[k]=zs[i];
    mind[k]=__builtin_huge_valf();
  }

  if (tid==0){ s_q[0]=xs[0]; s_q[1]=ys[0]; s_q[2]=zs[0]; }
  __syncthreads();

  for (int t=0; t<NSAMP-1; ++t){
    float qx=s_q[0], qy=s_q[1], qz=s_q[2];
    u64 m = 0ULL;
    #pragma unroll
    for (int k=0;k<PPT;k++){
      float d = dist2_exact(px[k],py[k],pz[k],qx,qy,qz);
      mind[k] = fminf(mind[k], d);
      u32 idx = (u32)(k*FPS_TOTAL + gt);
      u64 pk = ((u64)__float_as_uint(mind[k])<<32) | (u64)(0xFFFFFFFFu - idx);
      m = (pk>m)?pk:m;                 // max val; tie -> smaller idx wins
    }
    #pragma unroll
    for (int off=1; off<64; off<<=1){ u64 o=__shfl_xor(m,off,64); if(o>m)m=o; }
    if (lane==0) s_wmax[wv]=m;
    __syncthreads();
    if (wv==0){
      u64 wm = s_wmax[lane & (FPS_THREADS/64 - 1)];
      #pragma unroll
      for (int off=1; off<16; off<<=1){ u64 o=__shfl_xor(wm,off,64); if(o>wm)wm=o; }
      if (lane==0){
        __hip_atomic_store(&partials[(t&3)*FPS_BLOCKS + b], wm,
                           __ATOMIC_RELAXED, __HIP_MEMORY_SCOPE_AGENT);
        // re-arm the slot used two iterations from now (safe: ring depth 4)
        __hip_atomic_store(&partials[((t+2)&3)*FPS_BLOCKS + b], 0ULL,
                           __ATOMIC_RELAXED, __HIP_MEMORY_SCOPE_AGENT);
      }
      u64* slot = &partials[(t&3)*FPS_BLOCKS + (lane & (FPS_BLOCKS-1))];
      u64 v;
      do { v = __hip_atomic_load(slot, __ATOMIC_RELAXED, __HIP_MEMORY_SCOPE_AGENT); }
      while (v==0ULL);
      #pragma unroll
      for (int off=1; off<16; off<<=1){ u64 o=__shfl_xor(v,off,64); if(o>v)v=o; }
      u32 widx = 0xFFFFFFFFu - (u32)(v & 0xFFFFFFFFu);
      if (lane==0){
        s_q[0]=xs[widx]; s_q[1]=ys[widx]; s_q[2]=zs[widx];
        if (b==0) sample_inds[t+1]=widx;
      }
    }
    __syncthreads();
  }
}

// ---------------- K2: ball query + 25-NN (block per sample) ------------------
__global__ void __launch_bounds__(256) k_ballknn(
    const float* __restrict__ xs, const float* __restrict__ ys,
    const float* __restrict__ zs, const u32* __restrict__ sample_inds,
    u32* __restrict__ rad_inds, float* __restrict__ out_pts,
    float* __restrict__ out_cluster)
{
  __shared__ u64 s_list[CAND_CAP];
  __shared__ u64 s_red[4];
  __shared__ u64 s_win;
  __shared__ u32 s_cnt, s_first;
  const int s = blockIdx.x, tid = threadIdx.x;
  const u32 si = sample_inds[s];
  const float qx=xs[si], qy=ys[si], qz=zs[si];
  const float R2 = (float)(0.22*0.22);
  if (tid==0) s_cnt=0u;
  __syncthreads();

  for (int j=tid; j<N_PTS; j+=256){
    float d2 = dist2_exact(xs[j],ys[j],zs[j],qx,qy,qz);
    if (d2 <= R2){
      u32 pos = atomicAdd(&s_cnt,1u);
      if (pos < CAND_CAP) s_list[pos] = ((u64)__float_as_uint(d2)<<32) | (u64)j;
    }
  }
  __syncthreads();
  const int n = (int)min(s_cnt,(u32)CAND_CAP);

  for (int r=0; r<NB_; ++r){
    u64 m = ~0ULL; int mpos = -1;
    for (int p=tid; p<n; p+=256){
      u64 v=s_list[p];
      if (v<m){ m=v; mpos=p; }
    }
    u64 mm=m;
    #pragma unroll
    for (int off=1; off<64; off<<=1){ u64 o=__shfl_xor(mm,off,64); if(o<mm)mm=o; }
    if ((tid&63)==0) s_red[tid>>6]=mm;
    __syncthreads();
    if (tid==0){
      u64 w=s_red[0];
      #pragma unroll
      for (int i=1;i<4;i++) if (s_red[i]<w) w=s_red[i];
      s_win=w;
      if (r==0) s_first=(u32)(w & 0xFFFFFFFFu);
    }
    __syncthreads();
    u64 w = s_win;
    if (m==w && mpos>=0) s_list[mpos]=~0ULL;  // unique key -> exactly one marker
    if (tid==0){
      u32 widx = (r < n) ? (u32)(w & 0xFFFFFFFFu) : s_first; // pad = nearest
      int o = s*NB_ + r;
      rad_inds[o]=widx;
      out_pts[o*3+0]=xs[widx]; out_pts[o*3+1]=ys[widx]; out_pts[o*3+2]=zs[widx];
      out_cluster[o]=(float)s;
    }
    __syncthreads();
  }
}

// ---------------- K3: per-cluster MLP autoencoder ----------------------------
__global__ void __launch_bounds__(256) k_mlp(
    const float* __restrict__ xs, const float* __restrict__ ys,
    const float* __restrict__ zs, const u32* __restrict__ sample_inds,
    const u32* __restrict__ rad_inds,
    const float* __restrict__ ew1, const float* __restrict__ eb1,
    const float* __restrict__ ew2, const float* __restrict__ eb2,
    const float* __restrict__ ew3, const float* __restrict__ eb3,
    const float* __restrict__ dw1, const float* __restrict__ db1,
    const float* __restrict__ dw2, const float* __restrict__ db2,
    const float* __restrict__ dw3, const float* __restrict__ db3,
    float* __restrict__ out_deco)
{
  __shared__ float rel[NB_][3], mid[3];
  __shared__ float h1[NB_][80], h2[NB_][40], h3[NB_][20];
  __shared__ float feat[20], g1[40], g2[80];
  const int s=blockIdx.x, tid=threadIdx.x;

  if (tid==0){ u32 si=sample_inds[s]; mid[0]=xs[si]; mid[1]=ys[si]; mid[2]=zs[si]; }
  __syncthreads();
  if (tid < NB_){
    u32 ri = rad_inds[s*NB_+tid];
    rel[tid][0]=(xs[ri]-mid[0])/0.22f;
    rel[tid][1]=(ys[ri]-mid[1])/0.22f;
    rel[tid][2]=(zs[ri]-mid[2])/0.22f;
  }
  __syncthreads();
  for (int o=tid;o<NB_*80;o+=256){
    int p=o/80, f=o-p*80;
    float a=eb1[f]+rel[p][0]*ew1[0*80+f]+rel[p][1]*ew1[1*80+f]+rel[p][2]*ew1[2*80+f];
    h1[p][f]=fmaxf(a,0.f);
  }
  __syncthreads();
  for (int o=tid;o<NB_*40;o+=256){
    int p=o/40, f=o-p*40;
    float a=eb2[f];
    for (int k=0;k<80;k++) a += h1[p][k]*ew2[k*40+f];
    h2[p][f]=fmaxf(a,0.f);
  }
  __syncthreads();
  for (int o=tid;o<NB_*20;o+=256){
    int p=o/20, f=o-p*20;
    float a=eb3[f];
    for (int k=0;k<40;k++) a += h2[p][k]*ew3[k*20+f];
    h3[p][f]=fmaxf(a,0.f);
  }
  __syncthreads();
  if (tid<20){
    float m=h3[0][tid];
    for (int p=1;p<NB_;p++) m=fmaxf(m,h3[p][tid]);
    feat[tid]=m;
  }
  __syncthreads();
  if (tid<40){
    float a=db1[tid];
    for (int k=0;k<20;k++) a += feat[k]*dw1[k*40+tid];
    g1[tid]=fmaxf(a,0.f);
  }
  __syncthreads();
  if (tid<80){
    float a=db2[tid];
    for (int k=0;k<40;k++) a += g1[k]*dw2[k*80+tid];
    g2[tid]=fmaxf(a,0.f);
  }
  __syncthreads();
  if (tid<NB_*3){
    float a=db3[tid];
    for (int k=0;k<80;k++) a += g2[k]*dw3[k*75+tid];
    int p=tid/3, c=tid-p*3;
    out_deco[(s*NB_+p)*3+c] = a*0.22f + mid[c];
  }
}

// ---------------- launch -----------------------------------------------------
extern "C" void kernel_launch(void* const* d_in, const int* in_sizes, int n_in,
                              void* d_out, int out_size, void* d_ws, size_t ws_size,
                              hipStream_t stream){
  const float* pts=(const float*)d_in[0];
  const float* ew1=(const float*)d_in[1];  const float* eb1=(const float*)d_in[2];
  const float* ew2=(const float*)d_in[3];  const float* eb2=(const float*)d_in[4];
  const float* ew3=(const float*)d_in[5];  const float* eb3=(const float*)d_in[6];
  const float* dw1=(const float*)d_in[7];  const float* db1=(const float*)d_in[8];
  const float* dw2=(const float*)d_in[9];  const float* db2=(const float*)d_in[10];
  const float* dw3=(const float*)d_in[11]; const float* db3=(const float*)d_in[12];

  float* out = (float*)d_out;
  float* out_pts     = out;                 // [65550,3]
  float* out_cluster = out + NSAMP*NB_*3;   // [65550]
  float* out_deco    = out + NSAMP*NB_*4;   // [2622,25,3]

  char* ws = (char*)d_ws;
  float* xs = (float*)ws;
  float* ys = xs + N_PTS;
  float* zs = ys + N_PTS;
  u32* sinds    = (u32*)(zs + N_PTS);          // 2622 (padded region 4096)
  u64* partials = (u64*)(sinds + 4096);        // 4*16 u64 ring
  u32* rinds    = (u32*)(partials + 4*FPS_BLOCKS); // 65550 u32

  k_setup<<<(N_PTS+255)/256, 256, 0, stream>>>(pts, xs, ys, zs, sinds, partials);
  k_fps<<<FPS_BLOCKS, FPS_THREADS, 0, stream>>>(xs, ys, zs, sinds, partials);
  k_ballknn<<<NSAMP, 256, 0, stream>>>(xs, ys, zs, sinds, rinds, out_pts, out_cluster);
  k_mlp<<<NSAMP, 256, 0, stream>>>(xs, ys, zs, sinds, rinds,
                                   ew1,eb1,ew2,eb2,ew3,eb3,
                                   dw1,db1,dw2,db2,dw3,db3, out_deco);
}